// Round 5
// baseline (4509.026 us; speedup 1.0000x reference)
//
#include <hip/hip_runtime.h>
#include <math.h>

#define NN    10000
#define SSS   4
#define LL    8
#define HH    128
#define GG    384
#define NSEQ  40000
#define SUBN  100
#define ORIGF 64

#define MA 8
#define TA 384

typedef unsigned short u16;

__device__ __forceinline__ float bf2f(u16 u) {
  return __uint_as_float(((unsigned)u) << 16);
}
__device__ __forceinline__ u16 f2bf(float f) {
  unsigned u = __float_as_uint(f);
  u += 0x7fffu + ((u >> 16) & 1u);   // RNE
  return (u16)(u >> 16);
}
__device__ __forceinline__ void cvt8(uint4 v, float* f) {
  f[0] = __uint_as_float(v.x << 16);
  f[1] = __uint_as_float(v.x & 0xffff0000u);
  f[2] = __uint_as_float(v.y << 16);
  f[3] = __uint_as_float(v.y & 0xffff0000u);
  f[4] = __uint_as_float(v.z << 16);
  f[5] = __uint_as_float(v.z & 0xffff0000u);
  f[6] = __uint_as_float(v.w << 16);
  f[7] = __uint_as_float(v.w & 0xffff0000u);
}
__device__ __forceinline__ float sigmoidf_(float x) { return 1.f / (1.f + __expf(-x)); }
__device__ __forceinline__ float softplusf_(float x) {
  return fmaxf(x, 0.f) + log1pf(__expf(-fabsf(x)));
}

// acc[m] = bias + dot128(W[w0..], x0 + m*HH)   (fp32 LDS x, broadcast reads)
__device__ __forceinline__ void dots8(const float* __restrict__ W, int w0, float bias,
                                      const float* x0, float* acc) {
  #pragma unroll
  for (int m = 0; m < MA; ++m) acc[m] = bias;
  #pragma unroll 1
  for (int kc = 0; kc < HH; kc += 8) {
    const float4 wa = *(const float4*)(W + w0 + kc);
    const float4 wb = *(const float4*)(W + w0 + kc + 4);
    #pragma unroll
    for (int m = 0; m < MA; ++m) {
      const float* x = x0 + m * HH + kc;
      const float4 a = *(const float4*)(x);
      const float4 b = *(const float4*)(x + 4);
      float s = acc[m];
      s = fmaf(wa.x, a.x, s); s = fmaf(wa.y, a.y, s);
      s = fmaf(wa.z, a.z, s); s = fmaf(wa.w, a.w, s);
      s = fmaf(wb.x, b.x, s); s = fmaf(wb.y, b.y, s);
      s = fmaf(wb.z, b.z, s); s = fmaf(wb.w, b.w, s);
      acc[m] = s;
    }
  }
}

// ---------------- fused kernel: hT + loss partials ----------------
__global__ __launch_bounds__(TA, 4) void k_rum_fused(
    const float* __restrict__ hfeat, const float* __restrict__ y0,
    const float* __restrict__ Wih_w, const float* __restrict__ Whh_w,
    const float* __restrict__ bih_w, const float* __restrict__ bhh_w,
    const float* __restrict__ Wih,   const float* __restrict__ Whh,
    const float* __restrict__ bih,   const float* __restrict__ bhh,
    const float* __restrict__ W_ss,  const float* __restrict__ b_ss,
    const int* __restrict__ walks,   const int* __restrict__ idxs,
    float* __restrict__ out, float* __restrict__ ws)
{
  __shared__ float s_h[MA][HH];
  __shared__ float s_g[MA][GG];     // gate staging; reused as reduction buffer at end
  __shared__ float s_gn[MA][HH];
  __shared__ u16   s_yw[MA][LL][HH];  // walk-GRU outputs, bf16
  __shared__ int   s_wf[MA][LL];
  __shared__ int   s_uf[MA][LL];
  __shared__ int   s_cnt[MA];
  __shared__ int   s_any;

  const int tid = threadIdx.x;
  const int j = tid;                 // gate-row owned by this thread (0..383)
  const int q0 = blockIdx.x * MA;

  // ---- phase 0: walks, flip, first-occurrence; sample membership counts ----
  if (tid < MA) {
    const int m = tid;
    s_cnt[m] = 0;
    const int q = q0 + m;           // grid exact: q < NSEQ
    int w[LL];
    #pragma unroll
    for (int l = 0; l < LL; ++l) w[l] = walks[q * LL + l];
    #pragma unroll
    for (int l = 0; l < LL; ++l) {
      int u = l;
      #pragma unroll
      for (int l2 = LL - 1; l2 >= 0; --l2) if (w[l2] == w[l]) u = l2;
      s_wf[m][LL - 1 - l] = w[l];
      s_uf[m][LL - 1 - l] = u;
    }
  }
  if (tid == 0) s_any = 0;
  for (int idx = tid; idx < MA * HH; idx += TA) ((float*)s_h)[idx] = 0.f;
  __syncthreads();

  for (int p = tid; p < MA * SUBN; p += TA) {
    const int m = p / SUBN, i = p % SUBN;
    const int node = (q0 + m) % NN;
    if (idxs[i] == node) { atomicAdd(&s_cnt[m], 1); s_any = 1; }
  }

  const float bhhw_j = bhh_w[j];
  const float bih_j  = bih[j];
  const float bhh_j  = bhh[j];
  __syncthreads();

  // ---- phase A: walk GRU (input = one-hot -> column gather of Wih_w) ----
  for (int t = 0; t < LL; ++t) {
    {
      float acc[MA];
      dots8(Whh_w, j * HH, bhhw_j, &s_h[0][0], acc);
      #pragma unroll
      for (int m = 0; m < MA; ++m) s_g[m][j] = acc[m];
    }
    __syncthreads();
    for (int idx = tid; idx < MA * HH; idx += TA) {
      const int m = idx / HH, i = idx % HH;
      const int u = s_uf[m][t];
      const float gr = Wih_w[i * LL + u]            + bih_w[i];
      const float gz = Wih_w[(HH + i) * LL + u]     + bih_w[HH + i];
      const float gn = Wih_w[(2 * HH + i) * LL + u] + bih_w[2 * HH + i];
      const float r = sigmoidf_(gr + s_g[m][i]);
      const float z = sigmoidf_(gz + s_g[m][HH + i]);
      const float n = tanhf(gn + r * s_g[m][2 * HH + i]);
      const float hn = (1.f - z) * n + z * s_h[m][i];
      s_h[m][i] = hn;
      s_yw[m][t][i] = f2bf(hn);
    }
    __syncthreads();
  }

  // ---- phases B+C in halves of t: input gates barrier-free, then recurrence ----
  float pA = 0.f, pB = 0.f, pS = 0.f;

  #pragma unroll 1
  for (int half = 0; half < 2; ++half) {
    // phase B: gi[tt][m] = bih[j] + Wih[j,0:128]@hw + Wih[j,128:256]@y_walk
    float gi[4][MA];
    #pragma unroll
    for (int tt = 0; tt < 4; ++tt)
      #pragma unroll
      for (int m = 0; m < MA; ++m) gi[tt][m] = bih_j;

    #pragma unroll 1
    for (int kc = 0; kc < HH; kc += 8) {
      const float4 wa0 = *(const float4*)(Wih + j * (2 * HH) + kc);
      const float4 wa1 = *(const float4*)(Wih + j * (2 * HH) + kc + 4);
      const float4 wb0 = *(const float4*)(Wih + j * (2 * HH) + HH + kc);
      const float4 wb1 = *(const float4*)(Wih + j * (2 * HH) + HH + kc + 4);
      #pragma unroll
      for (int tt = 0; tt < 4; ++tt) {
        const int t = half * 4 + tt;
        #pragma unroll
        for (int m = 0; m < MA; ++m) {
          const float* hp = hfeat + (size_t)s_wf[m][t] * HH + kc;
          const float4 a = *(const float4*)(hp);
          const float4 b = *(const float4*)(hp + 4);
          float s = gi[tt][m];
          s = fmaf(wa0.x, a.x, s); s = fmaf(wa0.y, a.y, s);
          s = fmaf(wa0.z, a.z, s); s = fmaf(wa0.w, a.w, s);
          s = fmaf(wa1.x, b.x, s); s = fmaf(wa1.y, b.y, s);
          s = fmaf(wa1.z, b.z, s); s = fmaf(wa1.w, b.w, s);
          float yv[8];
          cvt8(*(const uint4*)(&s_yw[m][t][kc]), yv);
          s = fmaf(wb0.x, yv[0], s); s = fmaf(wb0.y, yv[1], s);
          s = fmaf(wb0.z, yv[2], s); s = fmaf(wb0.w, yv[3], s);
          s = fmaf(wb1.x, yv[4], s); s = fmaf(wb1.y, yv[5], s);
          s = fmaf(wb1.z, yv[6], s); s = fmaf(wb1.w, yv[7], s);
          gi[tt][m] = s;
        }
      }
    }

    // phase C: recurrence
    #pragma unroll
    for (int tt = 0; tt < 4; ++tt) {
      const int t = half * 4 + tt;
      float accg[MA];
      dots8(Whh, j * HH, bhh_j, &s_h[0][0], accg);
      if (j < 2 * HH) {
        #pragma unroll
        for (int m = 0; m < MA; ++m) s_g[m][j] = accg[m] + gi[tt][m];
      } else {
        #pragma unroll
        for (int m = 0; m < MA; ++m) { s_g[m][j] = accg[m]; s_gn[m][j - 2 * HH] = gi[tt][m]; }
      }
      __syncthreads();
      for (int idx = tid; idx < MA * HH; idx += TA) {
        const int m = idx / HH, i = idx % HH;
        const float r = sigmoidf_(s_g[m][i]);
        const float z = sigmoidf_(s_g[m][HH + i]);
        const float n = tanhf(s_gn[m][i] + r * s_g[m][2 * HH + i]);
        s_h[m][i] = (1.f - z) * n + z * s_h[m][i];
      }
      __syncthreads();

      // self-supervision BCE for sampled sequences (multiplicity-weighted)
      if (t < LL - 1 && s_any) {
        for (int idx = tid; idx < MA * ORIGF; idx += TA) {
          const int m = idx >> 6, o = idx & 63;
          const int c = s_cnt[m];
          if (c > 0) {
            const float* wr = W_ss + o * HH;
            float acc = b_ss[o];
            #pragma unroll 1
            for (int kc = 0; kc < HH; kc += 8) {
              const float4 wa = *(const float4*)(wr + kc);
              const float4 wb = *(const float4*)(wr + kc + 4);
              const float4 a = *(const float4*)(&s_h[m][kc]);
              const float4 b = *(const float4*)(&s_h[m][kc + 4]);
              acc = fmaf(wa.x, a.x, acc); acc = fmaf(wa.y, a.y, acc);
              acc = fmaf(wa.z, a.z, acc); acc = fmaf(wa.w, a.w, acc);
              acc = fmaf(wb.x, b.x, acc); acc = fmaf(wb.y, b.y, acc);
              acc = fmaf(wb.z, b.z, acc); acc = fmaf(wb.w, b.w, acc);
            }
            const float fc = (float)c;
            const float yt = y0[(size_t)s_wf[m][t + 1] * ORIGF + o];
            pA += fc * yt * softplusf_(-acc);
            pB += fc * (1.f - yt) * softplusf_(acc);
            pS += fc * yt;
          }
        }
      }
    }
  }

  // ---- epilogue: write hT; reduce loss partials ----
  for (int idx = tid; idx < MA * HH; idx += TA) {
    const int m = idx / HH, i = idx % HH;
    out[(size_t)(q0 + m) * HH + i] = s_h[m][i];
  }

  if (s_any) {
    float* red = &s_g[0][0];            // reuse s_g (3*TA = 1152 <= 3072 floats)
    red[tid] = pA; red[TA + tid] = pB; red[2 * TA + tid] = pS;
    __syncthreads();
    if (tid == 0) {
      float a = 0.f, b = 0.f, c = 0.f;
      for (int k = 0; k < TA; ++k) { a += red[k]; b += red[TA + k]; c += red[2 * TA + k]; }
      atomicAdd(&ws[1], a);
      atomicAdd(&ws[2], b);
      atomicAdd(&ws[3], c);
    }
  }
}

__global__ void k_zero(float* ws) {
  if (threadIdx.x < 4) ws[threadIdx.x] = 0.f;
}

__global__ void k_final(const float* __restrict__ ws, float* __restrict__ out) {
  if (threadIdx.x == 0) {
    const float cnt = (float)(SSS * SUBN * (LL - 1) * ORIGF);  // 179200
    const float pos_w = cnt / ws[3];
    const float loss = (pos_w * ws[1] + ws[2]) / cnt;
    out[NSEQ * HH] = loss;
  }
}

extern "C" void kernel_launch(void* const* d_in, const int* in_sizes, int n_in,
                              void* d_out, int out_size, void* d_ws, size_t ws_size,
                              hipStream_t stream) {
  const float* hfeat = (const float*)d_in[0];
  const float* y0    = (const float*)d_in[1];
  const float* Wih_w = (const float*)d_in[2];
  const float* Whh_w = (const float*)d_in[3];
  const float* bih_w = (const float*)d_in[4];
  const float* bhh_w = (const float*)d_in[5];
  const float* Wih   = (const float*)d_in[6];
  const float* Whh   = (const float*)d_in[7];
  const float* bih   = (const float*)d_in[8];
  const float* bhh   = (const float*)d_in[9];
  const float* W_ss  = (const float*)d_in[10];
  const float* b_ss  = (const float*)d_in[11];
  const int* walks = (const int*)d_in[12];
  const int* idxs  = (const int*)d_in[13];
  float* out = (float*)d_out;
  float* ws = (float*)d_ws;

  k_zero<<<1, 64, 0, stream>>>(ws);

  const int grid = NSEQ / MA;               // 5000, exact
  k_rum_fused<<<grid, TA, 0, stream>>>(hfeat, y0, Wih_w, Whh_w, bih_w, bhh_w,
                                       Wih, Whh, bih, bhh, W_ss, b_ss,
                                       walks, idxs, out, ws);

  k_final<<<1, 64, 0, stream>>>(ws, out);
}

// Round 6
// 3780.780 us; speedup vs baseline: 1.1926x; 1.1926x over previous
//
#include <hip/hip_runtime.h>
#include <math.h>

#define NN    10000
#define SSS   4
#define LL    8
#define HH    128
#define GG    384
#define NSEQ  40000
#define SUBN  100
#define ORIGF 64

#define MA 8
#define TA 384
#define QT 2   // timesteps per phase-B pass (register-pressure knob; 4 spilled at cap 64)

typedef unsigned short u16;

__device__ __forceinline__ float bf2f(u16 u) {
  return __uint_as_float(((unsigned)u) << 16);
}
__device__ __forceinline__ u16 f2bf(float f) {
  unsigned u = __float_as_uint(f);
  u += 0x7fffu + ((u >> 16) & 1u);   // RNE
  return (u16)(u >> 16);
}
__device__ __forceinline__ void cvt8(uint4 v, float* f) {
  f[0] = __uint_as_float(v.x << 16);
  f[1] = __uint_as_float(v.x & 0xffff0000u);
  f[2] = __uint_as_float(v.y << 16);
  f[3] = __uint_as_float(v.y & 0xffff0000u);
  f[4] = __uint_as_float(v.z << 16);
  f[5] = __uint_as_float(v.z & 0xffff0000u);
  f[6] = __uint_as_float(v.w << 16);
  f[7] = __uint_as_float(v.w & 0xffff0000u);
}
__device__ __forceinline__ float sigmoidf_(float x) { return 1.f / (1.f + __expf(-x)); }
__device__ __forceinline__ float softplusf_(float x) {
  return fmaxf(x, 0.f) + log1pf(__expf(-fabsf(x)));
}

// acc[m] = bias + dot128(W[w0..], x0 + m*HH)   (fp32 LDS x, broadcast reads)
__device__ __forceinline__ void dots8(const float* __restrict__ W, int w0, float bias,
                                      const float* x0, float* acc) {
  #pragma unroll
  for (int m = 0; m < MA; ++m) acc[m] = bias;
  #pragma unroll 1
  for (int kc = 0; kc < HH; kc += 8) {
    const float4 wa = *(const float4*)(W + w0 + kc);
    const float4 wb = *(const float4*)(W + w0 + kc + 4);
    #pragma unroll
    for (int m = 0; m < MA; ++m) {
      const float* x = x0 + m * HH + kc;
      const float4 a = *(const float4*)(x);
      const float4 b = *(const float4*)(x + 4);
      float s = acc[m];
      s = fmaf(wa.x, a.x, s); s = fmaf(wa.y, a.y, s);
      s = fmaf(wa.z, a.z, s); s = fmaf(wa.w, a.w, s);
      s = fmaf(wb.x, b.x, s); s = fmaf(wb.y, b.y, s);
      s = fmaf(wb.z, b.z, s); s = fmaf(wb.w, b.w, s);
      acc[m] = s;
    }
  }
}

// ---------------- fused kernel: hT + loss partials ----------------
__global__ __launch_bounds__(TA, 3) void k_rum_fused(
    const float* __restrict__ hfeat, const float* __restrict__ y0,
    const float* __restrict__ Wih_w, const float* __restrict__ Whh_w,
    const float* __restrict__ bih_w, const float* __restrict__ bhh_w,
    const float* __restrict__ Wih,   const float* __restrict__ Whh,
    const float* __restrict__ bih,   const float* __restrict__ bhh,
    const float* __restrict__ W_ss,  const float* __restrict__ b_ss,
    const int* __restrict__ walks,   const int* __restrict__ idxs,
    float* __restrict__ out, float* __restrict__ ws)
{
  __shared__ float s_h[MA][HH];
  __shared__ float s_g[MA][GG];     // gate staging; reused as reduction buffer at end
  __shared__ float s_gn[MA][HH];
  __shared__ u16   s_yw[MA][LL][HH];  // walk-GRU outputs, bf16
  __shared__ int   s_wf[MA][LL];
  __shared__ int   s_uf[MA][LL];
  __shared__ int   s_cnt[MA];
  __shared__ int   s_any;

  const int tid = threadIdx.x;
  const int j = tid;                 // gate-row owned by this thread (0..383)
  const int q0 = blockIdx.x * MA;

  // ---- phase 0: walks, flip, first-occurrence; sample membership counts ----
  if (tid < MA) {
    const int m = tid;
    s_cnt[m] = 0;
    const int q = q0 + m;           // grid exact: q < NSEQ
    int w[LL];
    #pragma unroll
    for (int l = 0; l < LL; ++l) w[l] = walks[q * LL + l];
    #pragma unroll
    for (int l = 0; l < LL; ++l) {
      int u = l;
      #pragma unroll
      for (int l2 = LL - 1; l2 >= 0; --l2) if (w[l2] == w[l]) u = l2;
      s_wf[m][LL - 1 - l] = w[l];
      s_uf[m][LL - 1 - l] = u;
    }
  }
  if (tid == 0) s_any = 0;
  for (int idx = tid; idx < MA * HH; idx += TA) ((float*)s_h)[idx] = 0.f;
  __syncthreads();

  for (int p = tid; p < MA * SUBN; p += TA) {
    const int m = p / SUBN, i = p % SUBN;
    const int node = (q0 + m) % NN;
    if (idxs[i] == node) { atomicAdd(&s_cnt[m], 1); s_any = 1; }
  }

  const float bhhw_j = bhh_w[j];
  const float bih_j  = bih[j];
  const float bhh_j  = bhh[j];
  __syncthreads();

  // ---- phase A: walk GRU (input = one-hot -> column gather of Wih_w) ----
  for (int t = 0; t < LL; ++t) {
    {
      float acc[MA];
      dots8(Whh_w, j * HH, bhhw_j, &s_h[0][0], acc);
      #pragma unroll
      for (int m = 0; m < MA; ++m) s_g[m][j] = acc[m];
    }
    __syncthreads();
    for (int idx = tid; idx < MA * HH; idx += TA) {
      const int m = idx / HH, i = idx % HH;
      const int u = s_uf[m][t];
      const float gr = Wih_w[i * LL + u]            + bih_w[i];
      const float gz = Wih_w[(HH + i) * LL + u]     + bih_w[HH + i];
      const float gn = Wih_w[(2 * HH + i) * LL + u] + bih_w[2 * HH + i];
      const float r = sigmoidf_(gr + s_g[m][i]);
      const float z = sigmoidf_(gz + s_g[m][HH + i]);
      const float n = tanhf(gn + r * s_g[m][2 * HH + i]);
      const float hn = (1.f - z) * n + z * s_h[m][i];
      s_h[m][i] = hn;
      s_yw[m][t][i] = f2bf(hn);
    }
    __syncthreads();
  }

  // ---- phases B+C in passes of QT timesteps ----
  float pA = 0.f, pB = 0.f, pS = 0.f;

  #pragma unroll 1
  for (int pass = 0; pass < LL / QT; ++pass) {
    // phase B: gi[tt][m] = bih[j] + Wih[j,0:128]@hw + Wih[j,128:256]@y_walk
    float gi[QT][MA];
    #pragma unroll
    for (int tt = 0; tt < QT; ++tt)
      #pragma unroll
      for (int m = 0; m < MA; ++m) gi[tt][m] = bih_j;

    #pragma unroll 1
    for (int kc = 0; kc < HH; kc += 8) {
      const float4 wa0 = *(const float4*)(Wih + j * (2 * HH) + kc);
      const float4 wa1 = *(const float4*)(Wih + j * (2 * HH) + kc + 4);
      const float4 wb0 = *(const float4*)(Wih + j * (2 * HH) + HH + kc);
      const float4 wb1 = *(const float4*)(Wih + j * (2 * HH) + HH + kc + 4);
      #pragma unroll
      for (int tt = 0; tt < QT; ++tt) {
        const int t = pass * QT + tt;
        #pragma unroll
        for (int m = 0; m < MA; ++m) {
          const float* hp = hfeat + (size_t)s_wf[m][t] * HH + kc;
          const float4 a = *(const float4*)(hp);
          const float4 b = *(const float4*)(hp + 4);
          float s = gi[tt][m];
          s = fmaf(wa0.x, a.x, s); s = fmaf(wa0.y, a.y, s);
          s = fmaf(wa0.z, a.z, s); s = fmaf(wa0.w, a.w, s);
          s = fmaf(wa1.x, b.x, s); s = fmaf(wa1.y, b.y, s);
          s = fmaf(wa1.z, b.z, s); s = fmaf(wa1.w, b.w, s);
          float yv[8];
          cvt8(*(const uint4*)(&s_yw[m][t][kc]), yv);
          s = fmaf(wb0.x, yv[0], s); s = fmaf(wb0.y, yv[1], s);
          s = fmaf(wb0.z, yv[2], s); s = fmaf(wb0.w, yv[3], s);
          s = fmaf(wb1.x, yv[4], s); s = fmaf(wb1.y, yv[5], s);
          s = fmaf(wb1.z, yv[6], s); s = fmaf(wb1.w, yv[7], s);
          gi[tt][m] = s;
        }
      }
    }

    // phase C: recurrence
    #pragma unroll
    for (int tt = 0; tt < QT; ++tt) {
      const int t = pass * QT + tt;
      float accg[MA];
      dots8(Whh, j * HH, bhh_j, &s_h[0][0], accg);
      if (j < 2 * HH) {
        #pragma unroll
        for (int m = 0; m < MA; ++m) s_g[m][j] = accg[m] + gi[tt][m];
      } else {
        #pragma unroll
        for (int m = 0; m < MA; ++m) { s_g[m][j] = accg[m]; s_gn[m][j - 2 * HH] = gi[tt][m]; }
      }
      __syncthreads();
      for (int idx = tid; idx < MA * HH; idx += TA) {
        const int m = idx / HH, i = idx % HH;
        const float r = sigmoidf_(s_g[m][i]);
        const float z = sigmoidf_(s_g[m][HH + i]);
        const float n = tanhf(s_gn[m][i] + r * s_g[m][2 * HH + i]);
        s_h[m][i] = (1.f - z) * n + z * s_h[m][i];
      }
      __syncthreads();

      // self-supervision BCE for sampled sequences (multiplicity-weighted)
      if (t < LL - 1 && s_any) {
        for (int idx = tid; idx < MA * ORIGF; idx += TA) {
          const int m = idx >> 6, o = idx & 63;
          const int c = s_cnt[m];
          if (c > 0) {
            const float* wr = W_ss + o * HH;
            float acc = b_ss[o];
            #pragma unroll 1
            for (int kc = 0; kc < HH; kc += 8) {
              const float4 wa = *(const float4*)(wr + kc);
              const float4 wb = *(const float4*)(wr + kc + 4);
              const float4 a = *(const float4*)(&s_h[m][kc]);
              const float4 b = *(const float4*)(&s_h[m][kc + 4]);
              acc = fmaf(wa.x, a.x, acc); acc = fmaf(wa.y, a.y, acc);
              acc = fmaf(wa.z, a.z, acc); acc = fmaf(wa.w, a.w, acc);
              acc = fmaf(wb.x, b.x, acc); acc = fmaf(wb.y, b.y, acc);
              acc = fmaf(wb.z, b.z, acc); acc = fmaf(wb.w, b.w, acc);
            }
            const float fc = (float)c;
            const float yt = y0[(size_t)s_wf[m][t + 1] * ORIGF + o];
            pA += fc * yt * softplusf_(-acc);
            pB += fc * (1.f - yt) * softplusf_(acc);
            pS += fc * yt;
          }
        }
      }
    }
  }

  // ---- epilogue: write hT; reduce loss partials ----
  for (int idx = tid; idx < MA * HH; idx += TA) {
    const int m = idx / HH, i = idx % HH;
    out[(size_t)(q0 + m) * HH + i] = s_h[m][i];
  }

  if (s_any) {
    float* red = &s_g[0][0];            // reuse s_g (3*TA = 1152 <= 3072 floats)
    red[tid] = pA; red[TA + tid] = pB; red[2 * TA + tid] = pS;
    __syncthreads();
    if (tid == 0) {
      float a = 0.f, b = 0.f, c = 0.f;
      for (int k = 0; k < TA; ++k) { a += red[k]; b += red[TA + k]; c += red[2 * TA + k]; }
      atomicAdd(&ws[1], a);
      atomicAdd(&ws[2], b);
      atomicAdd(&ws[3], c);
    }
  }
}

__global__ void k_zero(float* ws) {
  if (threadIdx.x < 4) ws[threadIdx.x] = 0.f;
}

__global__ void k_final(const float* __restrict__ ws, float* __restrict__ out) {
  if (threadIdx.x == 0) {
    const float cnt = (float)(SSS * SUBN * (LL - 1) * ORIGF);  // 179200
    const float pos_w = cnt / ws[3];
    const float loss = (pos_w * ws[1] + ws[2]) / cnt;
    out[NSEQ * HH] = loss;
  }
}

extern "C" void kernel_launch(void* const* d_in, const int* in_sizes, int n_in,
                              void* d_out, int out_size, void* d_ws, size_t ws_size,
                              hipStream_t stream) {
  const float* hfeat = (const float*)d_in[0];
  const float* y0    = (const float*)d_in[1];
  const float* Wih_w = (const float*)d_in[2];
  const float* Whh_w = (const float*)d_in[3];
  const float* bih_w = (const float*)d_in[4];
  const float* bhh_w = (const float*)d_in[5];
  const float* Wih   = (const float*)d_in[6];
  const float* Whh   = (const float*)d_in[7];
  const float* bih   = (const float*)d_in[8];
  const float* bhh   = (const float*)d_in[9];
  const float* W_ss  = (const float*)d_in[10];
  const float* b_ss  = (const float*)d_in[11];
  const int* walks = (const int*)d_in[12];
  const int* idxs  = (const int*)d_in[13];
  float* out = (float*)d_out;
  float* ws = (float*)d_ws;

  k_zero<<<1, 64, 0, stream>>>(ws);

  const int grid = NSEQ / MA;               // 5000, exact
  k_rum_fused<<<grid, TA, 0, stream>>>(hfeat, y0, Wih_w, Whh_w, bih_w, bhh_w,
                                       Wih, Whh, bih, bhh, W_ss, b_ss,
                                       walks, idxs, out, ws);

  k_final<<<1, 64, 0, stream>>>(ws, out);
}

// Round 7
// 945.801 us; speedup vs baseline: 4.7674x; 3.9974x over previous
//
#include <hip/hip_runtime.h>
#include <math.h>

#define NN    10000
#define SSS   4
#define LL    8
#define HH    128
#define GG    384
#define NSEQ  40000
#define SUBN  100
#define ORIGF 64
#define MA    16
#define TA    384

typedef unsigned short u16;
typedef short bf16x8 __attribute__((ext_vector_type(8)));
typedef float f32x4 __attribute__((ext_vector_type(4)));

// ---- LDS layout (bytes); strides chosen for 16B alignment + <=2-way banks ----
#define XB_STR   264            // u16 cols per row (256 + 8 pad)
#define XB_OFF   0              // u16[64][264]  phase-B A-staging (one t-half)
#define HB_OFF   33792          // u16[16][136]  bf16 h-state mirror
#define HB_STR   136
#define SG_OFF   38144          // f32[16][385]  gate staging
#define SG_STR   385
#define SGN_OFF  62784          // f32[16][132]  gi_n staging (phase C)
#define SGN_STR  132
#define SH_OFF   71232          // f32[16][128]  fp32 master h
#define SWF_OFF  79424          // int[16][8] flipped walks
#define SUF_OFF  79936          // int[16][8] first-occurrence idx
#define SCNT_OFF 80448          // int[16] sample multiplicity
#define SANY_OFF 80512          // int
#define LDS_TOTAL 80528

// ws layout: ws[0..3] accum; byte 64: bf16 weights (whhw|whh|wih)
#define WB_BYTE_OFF 64
#define W_HHW_N 49152           // 384*128
#define W_HH_N  49152
#define W_IH_N  98304           // 384*256
#define W_TOTAL (W_HHW_N + W_HH_N + W_IH_N)   // 196608

__device__ __forceinline__ u16 f2bf(float f) {
  unsigned u = __float_as_uint(f);
  u += 0x7fffu + ((u >> 16) & 1u);   // RNE
  return (u16)(u >> 16);
}
__device__ __forceinline__ float sigmoidf_(float x) { return 1.f / (1.f + __expf(-x)); }
__device__ __forceinline__ float softplusf_(float x) {
  return fmaxf(x, 0.f) + log1pf(__expf(-fabsf(x)));
}

__global__ void k_zero(float* ws) {
  if (threadIdx.x < 4) ws[threadIdx.x] = 0.f;
}

// convert the three MFMA weight matrices to bf16 in ws
__global__ void k_prep(const float* __restrict__ whhw, const float* __restrict__ whh,
                       const float* __restrict__ wih, float* __restrict__ ws) {
  const int i = blockIdx.x * 256 + threadIdx.x;   // grid sized exactly W_TOTAL/256
  u16* wb = (u16*)((char*)ws + WB_BYTE_OFF);
  if (i < W_HHW_N)                wb[i] = f2bf(whhw[i]);
  else if (i < W_HHW_N + W_HH_N)  wb[i] = f2bf(whh[i - W_HHW_N]);
  else                            wb[i] = f2bf(wih[i - W_HHW_N - W_HH_N]);
}

// stage hfeat rows (bf16) for t-half `half` into xb cols 0..127
__device__ __forceinline__ void stageH(const float* __restrict__ hfeat, u16* xb,
                                       const int* swf, int half, int tid) {
  for (int idx = tid; idx < 64 * 32; idx += TA) {
    const int r = idx >> 5, ch = idx & 31;
    const int t = half * 4 + (r >> 4), m = r & 15;
    const float4 v = *(const float4*)(hfeat + (size_t)swf[m * LL + t] * HH + ch * 4);
    u16* dst = xb + r * XB_STR + ch * 4;
    dst[0] = f2bf(v.x); dst[1] = f2bf(v.y); dst[2] = f2bf(v.z); dst[3] = f2bf(v.w);
  }
}

// phase B t-half: gi[H*4+mt][n] += A(xb rows) * BW  (no barriers, wave-local)
template<int H>
__device__ __forceinline__ void phaseB(const u16* xb, const bf16x8 (&BW)[4][8],
                                       f32x4 (&gi)[8][4], int c, int qd) {
  #pragma unroll
  for (int mt = 0; mt < 4; ++mt) {
    bf16x8 a2[8];
    #pragma unroll
    for (int kt = 0; kt < 8; ++kt)
      a2[kt] = *(const bf16x8*)(xb + (mt * 16 + c) * XB_STR + kt * 32 + qd * 8);
    #pragma unroll
    for (int n = 0; n < 4; ++n)
      #pragma unroll
      for (int kt = 0; kt < 8; ++kt)
        gi[H * 4 + mt][n] = __builtin_amdgcn_mfma_f32_16x16x32_bf16(
            a2[kt], BW[n][kt], gi[H * 4 + mt][n], 0, 0, 0);
  }
}

__global__ __launch_bounds__(TA, 1) void k_rum(
    const float* __restrict__ hfeat, const float* __restrict__ y0,
    const float* __restrict__ WihW,  const float* __restrict__ bihW,
    const float* __restrict__ bhhW,
    const float* __restrict__ bih,   const float* __restrict__ bhh,
    const float* __restrict__ W_ss,  const float* __restrict__ b_ss,
    const int* __restrict__ walks,   const int* __restrict__ idxs,
    float* __restrict__ out, float* __restrict__ ws)
{
  extern __shared__ char sm[];
  u16*   xb  = (u16*)(sm + XB_OFF);
  u16*   hb  = (u16*)(sm + HB_OFF);
  float* sg  = (float*)(sm + SG_OFF);
  float* sgn = (float*)(sm + SGN_OFF);
  float* sh  = (float*)(sm + SH_OFF);
  int*   swf = (int*)(sm + SWF_OFF);
  int*   suf = (int*)(sm + SUF_OFF);
  int*   scnt= (int*)(sm + SCNT_OFF);
  int*   sany= (int*)(sm + SANY_OFF);

  const u16* wb     = (const u16*)((const char*)ws + WB_BYTE_OFF);
  const u16* whhw_b = wb;
  const u16* whh_b  = wb + W_HHW_N;
  const u16* wih_b  = wb + W_HHW_N + W_HH_N;

  const int tid = threadIdx.x;
  const int lane = tid & 63, c = lane & 15, qd = lane >> 4;
  const int wv = tid >> 6, col0 = wv * 64;
  const int q0 = blockIdx.x * MA;

  // ---- phase 0: walks, flip, first-occurrence ----
  if (tid < MA) {
    const int m = tid;
    scnt[m] = 0;
    const int q = q0 + m;
    int w[LL];
    #pragma unroll
    for (int l = 0; l < LL; ++l) w[l] = walks[q * LL + l];
    #pragma unroll
    for (int l = 0; l < LL; ++l) {
      int u = l;
      #pragma unroll
      for (int l2 = LL - 1; l2 >= 0; --l2) if (w[l2] == w[l]) u = l2;
      swf[m * LL + (LL - 1 - l)] = w[l];
      suf[m * LL + (LL - 1 - l)] = u;
    }
  }
  if (tid == 0) *sany = 0;
  for (int idx = tid; idx < MA * HH; idx += TA) {
    sh[idx] = 0.f;
    hb[(idx >> 7) * HB_STR + (idx & 127)] = 0;
  }
  __syncthreads();

  // membership (multiplicity-aware)
  for (int p = tid; p < MA * SUBN; p += TA) {
    const int m = p / SUBN, i = p % SUBN;
    if (idxs[i] == (q0 + m) % NN) { atomicAdd(&scnt[m], 1); *sany = 1; }
  }

  stageH(hfeat, xb, swf, 0, tid);

  // ---- preload B-fragments: Whh_w (phase A) and Wih (phase B) ----
  bf16x8 BA[4][4];
  #pragma unroll
  for (int n = 0; n < 4; ++n)
    #pragma unroll
    for (int k = 0; k < 4; ++k)
      BA[n][k] = *(const bf16x8*)(whhw_b + (col0 + n * 16 + c) * HH + k * 32 + qd * 8);
  bf16x8 BW[4][8];
  #pragma unroll
  for (int n = 0; n < 4; ++n)
    #pragma unroll
    for (int kt = 0; kt < 8; ++kt)
      BW[n][kt] = *(const bf16x8*)(wih_b + (col0 + n * 16 + c) * 256 + kt * 32 + qd * 8);

  f32x4 gi[8][4];
  #pragma unroll
  for (int t = 0; t < 8; ++t)
    #pragma unroll
    for (int n = 0; n < 4; ++n)
      gi[t][n] = (f32x4){0.f, 0.f, 0.f, 0.f};

  float pAcc = 0.f, pBcc = 0.f, pScc = 0.f;

  // ---- phase A (walk GRU) + phase B, interleaved by t-halves ----
  #pragma unroll 1
  for (int t = 0; t < LL; ++t) {
    // gh = h_walk @ Whh_w^T via MFMA
    bf16x8 a[4];
    #pragma unroll
    for (int k = 0; k < 4; ++k)
      a[k] = *(const bf16x8*)(hb + c * HB_STR + k * 32 + qd * 8);
    #pragma unroll
    for (int n = 0; n < 4; ++n) {
      f32x4 d = {0.f, 0.f, 0.f, 0.f};
      #pragma unroll
      for (int k = 0; k < 4; ++k)
        d = __builtin_amdgcn_mfma_f32_16x16x32_bf16(a[k], BA[n][k], d, 0, 0, 0);
      #pragma unroll
      for (int reg = 0; reg < 4; ++reg)
        sg[(qd * 4 + reg) * SG_STR + col0 + n * 16 + c] = d[reg];
    }
    __syncthreads();
    // activation (gi from one-hot gather of Wih_w, fp32)
    for (int idx = tid; idx < MA * HH; idx += TA) {
      const int m = idx >> 7, i = idx & 127;
      const int u = suf[m * LL + t];
      const float gir = WihW[i * LL + u] + bihW[i];
      const float giz = WihW[(HH + i) * LL + u] + bihW[HH + i];
      const float gin = WihW[(2 * HH + i) * LL + u] + bihW[2 * HH + i];
      const float ghr = sg[m * SG_STR + i] + bhhW[i];
      const float ghz = sg[m * SG_STR + HH + i] + bhhW[HH + i];
      const float ghn = sg[m * SG_STR + 2 * HH + i] + bhhW[2 * HH + i];
      const float r = sigmoidf_(gir + ghr);
      const float z = sigmoidf_(giz + ghz);
      const float n = tanhf(gin + r * ghn);
      const float hn = (1.f - z) * n + z * sh[m * HH + i];
      sh[m * HH + i] = hn;
      const u16 hv = f2bf(hn);
      hb[m * HB_STR + i] = hv;
      xb[((t & 3) * 16 + m) * XB_STR + HH + i] = hv;
    }
    __syncthreads();

    if (t == 3) {
      phaseB<0>(xb, BW, gi, c, qd);
      __syncthreads();             // all waves done reading xb half-0
      stageH(hfeat, xb, swf, 1, tid);
    }
  }
  phaseB<1>(xb, BW, gi, c, qd);

  // ---- preload Whh B-frags for phase C ----
  bf16x8 BC[4][4];
  #pragma unroll
  for (int n = 0; n < 4; ++n)
    #pragma unroll
    for (int k = 0; k < 4; ++k)
      BC[n][k] = *(const bf16x8*)(whh_b + (col0 + n * 16 + c) * HH + k * 32 + qd * 8);

  // ---- phase C (main GRU), t unrolled so gi[t] stays in registers ----
  #pragma unroll
  for (int t = 0; t < LL; ++t) {
    bf16x8 a[4];
    #pragma unroll
    for (int k = 0; k < 4; ++k)
      a[k] = *(const bf16x8*)(hb + c * HB_STR + k * 32 + qd * 8);
    #pragma unroll
    for (int n = 0; n < 4; ++n) {
      f32x4 d = {0.f, 0.f, 0.f, 0.f};
      #pragma unroll
      for (int k = 0; k < 4; ++k)
        d = __builtin_amdgcn_mfma_f32_16x16x32_bf16(a[k], BC[n][k], d, 0, 0, 0);
      if (wv < 4) {                     // r,z gate rows: store gh+gi sum
        #pragma unroll
        for (int reg = 0; reg < 4; ++reg)
          sg[(qd * 4 + reg) * SG_STR + col0 + n * 16 + c] = d[reg] + gi[t][n][reg];
      } else {                          // n gate rows: keep gh and gi separate
        #pragma unroll
        for (int reg = 0; reg < 4; ++reg) {
          const int row = qd * 4 + reg;
          sg[row * SG_STR + col0 + n * 16 + c] = d[reg];
          sgn[row * SGN_STR + (col0 - 2 * HH) + n * 16 + c] = gi[t][n][reg];
        }
      }
    }
    __syncthreads();
    for (int idx = tid; idx < MA * HH; idx += TA) {
      const int m = idx >> 7, i = idx & 127;
      const float r = sigmoidf_(sg[m * SG_STR + i] + bih[i] + bhh[i]);
      const float z = sigmoidf_(sg[m * SG_STR + HH + i] + bih[HH + i] + bhh[HH + i]);
      const float n = tanhf(sgn[m * SGN_STR + i] + bih[2 * HH + i]
                            + r * (sg[m * SG_STR + 2 * HH + i] + bhh[2 * HH + i]));
      const float hn = (1.f - z) * n + z * sh[m * HH + i];
      sh[m * HH + i] = hn;
      hb[m * HB_STR + i] = f2bf(hn);
    }
    __syncthreads();

    if (t < LL - 1 && *sany) {
      for (int idx = tid; idx < MA * ORIGF; idx += TA) {
        const int m = idx >> 6, o = idx & 63;
        const int cnt = scnt[m];
        if (cnt > 0) {
          const float* wr = W_ss + o * HH;
          float acc = b_ss[o];
          #pragma unroll 1
          for (int kc = 0; kc < HH; kc += 8) {
            const float4 wa = *(const float4*)(wr + kc);
            const float4 wb4 = *(const float4*)(wr + kc + 4);
            const float4 xa = *(const float4*)(&sh[m * HH + kc]);
            const float4 xb4 = *(const float4*)(&sh[m * HH + kc + 4]);
            acc = fmaf(wa.x, xa.x, acc); acc = fmaf(wa.y, xa.y, acc);
            acc = fmaf(wa.z, xa.z, acc); acc = fmaf(wa.w, xa.w, acc);
            acc = fmaf(wb4.x, xb4.x, acc); acc = fmaf(wb4.y, xb4.y, acc);
            acc = fmaf(wb4.z, xb4.z, acc); acc = fmaf(wb4.w, xb4.w, acc);
          }
          const float fc = (float)cnt;
          const float yt = y0[(size_t)swf[m * LL + t + 1] * ORIGF + o];
          pAcc += fc * yt * softplusf_(-acc);
          pBcc += fc * (1.f - yt) * softplusf_(acc);
          pScc += fc * yt;
        }
      }
    }
  }

  // ---- epilogue: hT + loss reduction ----
  for (int idx = tid; idx < MA * HH; idx += TA)
    out[(size_t)(q0 + (idx >> 7)) * HH + (idx & 127)] = sh[idx];

  if (*sany) {
    float* red = sg;                   // reuse (3*TA = 1152 <= 16*385)
    red[tid] = pAcc; red[TA + tid] = pBcc; red[2 * TA + tid] = pScc;
    __syncthreads();
    if (tid == 0) {
      float a = 0.f, b = 0.f, s = 0.f;
      for (int k = 0; k < TA; ++k) { a += red[k]; b += red[TA + k]; s += red[2 * TA + k]; }
      atomicAdd(&ws[1], a);
      atomicAdd(&ws[2], b);
      atomicAdd(&ws[3], s);
    }
  }
}

__global__ void k_final(const float* __restrict__ ws, float* __restrict__ out) {
  if (threadIdx.x == 0) {
    const float cnt = (float)(SSS * SUBN * (LL - 1) * ORIGF);  // 179200
    const float pos_w = cnt / ws[3];
    const float loss = (pos_w * ws[1] + ws[2]) / cnt;
    out[NSEQ * HH] = loss;
  }
}

extern "C" void kernel_launch(void* const* d_in, const int* in_sizes, int n_in,
                              void* d_out, int out_size, void* d_ws, size_t ws_size,
                              hipStream_t stream) {
  const float* hfeat = (const float*)d_in[0];
  const float* y0    = (const float*)d_in[1];
  const float* Wih_w = (const float*)d_in[2];
  const float* Whh_w = (const float*)d_in[3];
  const float* bih_w = (const float*)d_in[4];
  const float* bhh_w = (const float*)d_in[5];
  const float* Wih   = (const float*)d_in[6];
  const float* Whh   = (const float*)d_in[7];
  const float* bih   = (const float*)d_in[8];
  const float* bhh   = (const float*)d_in[9];
  const float* W_ss  = (const float*)d_in[10];
  const float* b_ss  = (const float*)d_in[11];
  const int* walks = (const int*)d_in[12];
  const int* idxs  = (const int*)d_in[13];
  float* out = (float*)d_out;
  float* ws = (float*)d_ws;

  (void)hipFuncSetAttribute((const void*)k_rum,
                            hipFuncAttributeMaxDynamicSharedMemorySize, LDS_TOTAL);

  k_zero<<<1, 64, 0, stream>>>(ws);
  k_prep<<<W_TOTAL / 256, 256, 0, stream>>>(Whh_w, Whh, Wih, ws);

  const int grid = NSEQ / MA;               // 2500, exact
  k_rum<<<grid, TA, LDS_TOTAL, stream>>>(hfeat, y0, Wih_w, bih_w, bhh_w,
                                         bih, bhh, W_ss, b_ss,
                                         walks, idxs, out, ws);

  k_final<<<1, 64, 0, stream>>>(ws, out);
}